// Round 9
// baseline (198.597 us; speedup 1.0000x reference)
//
#include <hip/hip_runtime.h>

// ---------------- problem constants ----------------
#define NBLK   98304     // 8*3*64*64 total 8x8 blocks
#define NPB    12288     // blocks per batch (3*64*64)
#define HW     512
#define NUMBITS 4096
#define RANK0  29490     // floor(0.3*(NBLK-1))
#define RANK1  29491
#define STEGO_N 6291456  // 8*3*512*512
#define ELIG   111       // ceil(4096/37) blocks contain eligible coefficients
#define HISTB  512       // fixed bins over variance range [0, 0.25]
#define CCAP   4096
#define NWG    384       // k_stats workgroups

typedef unsigned long long ull;

// ---------------- DCT matrix as compile-time constants ----------------
struct DTab { double d[8][8]; };

constexpr double CT_[9] = {
  1.0,
  0.98078528040323044913,
  0.92387953251128675613,
  0.83146961230254523708,
  0.70710678118654752440,
  0.55557023301960222474,
  0.38268343236508977173,
  0.19509032201612826785,
  0.0
};
constexpr double cospi16(int m){           // cos(pi*m/16), m >= 0
  int r = m % 32;
  return (r<=8) ? CT_[r] : (r<=16) ? -CT_[16-r] : (r<=24) ? -CT_[r-16] : CT_[32-r];
}
constexpr DTab make_dtab(){
  DTab t{};
  for(int k=0;k<8;k++) for(int n=0;n<8;n++){
    double s = (k==0) ? 0.35355339059327376220 : 0.5; // sqrt(1/8), sqrt(2/8)
    t.d[k][n] = s * cospi16((2*n+1)*k);
  }
  return t;
}
constexpr DTab DT = make_dtab();

constexpr ull make_fmask(){ // bit u*8+v set iff 3 <= u+v <= 8
  ull m = 0;
  for(int u=0;u<8;u++) for(int v=0;v<8;v++){
    int s=u+v; if(s>=3 && s<=8) m |= (1ULL << (u*8+v));
  }
  return m;
}
constexpr ull FMASK = make_fmask();  // 37 bits set

__device__ __forceinline__ int binof(double v){
  int b = (int)(v * 2048.0);                // HISTB/0.25 — fixed, deterministic
  if(b > HISTB-1) b = HISTB-1;
  return b;                                 // v >= 0 always
}

// ---------------- D1: copy + map-zero + variance + per-WG histogram ----------------
__global__ __launch_bounds__(256) void k_stats(const float* __restrict__ cover,
    float* __restrict__ out, double* __restrict__ var,
    unsigned* __restrict__ histp, unsigned* __restrict__ cand_cnt){
  __shared__ unsigned h[HISTB];             // 2 KB
  int tid = threadIdx.x;
  int i = blockIdx.x*256 + tid;             // block id over (b,c,n,m)
  if(tid < HISTB/128) { h[tid*128 + (tid&127)] = 0u; }   // (dummy; real zero below)
  for(int j=tid;j<HISTB;j+=256) h[j]=0u;
  if(blockIdx.x==0 && tid==0) *cand_cnt = 0u;
  int m = i & 63, n = (i>>6)&63, bc = i>>12;
  const float* p  = cover + ((size_t)bc*HW + (size_t)n*8)*HW + (size_t)m*8;
  float*       po = out   + ((size_t)bc*HW + (size_t)n*8)*HW + (size_t)m*8;
  double s1=0.0, s2=0.0;
#pragma unroll
  for(int r=0;r<8;r++){
    const float4* q = (const float4*)(p + (size_t)r*HW);
    float4 a = q[0], b = q[1];
    float4* w = (float4*)(po + (size_t)r*HW);
    w[0]=a; w[1]=b;
    double x;
    x=(double)a.x; s1+=x; s2+=x*x;
    x=(double)a.y; s1+=x; s2+=x*x;
    x=(double)a.z; s1+=x; s2+=x*x;
    x=(double)a.w; s1+=x; s2+=x*x;
    x=(double)b.x; s1+=x; s2+=x*x;
    x=(double)b.y; s1+=x; s2+=x*x;
    x=(double)b.z; s1+=x; s2+=x*x;
    x=(double)b.w; s1+=x; s2+=x*x;
  }
  double mean = s1*(1.0/64.0);
  double v = s2*(1.0/64.0) - mean*mean;
  if(v < 0.0) v = 0.0;
  var[i] = v;
  // zero this block's embedding map (fixed up later for eligible blocks)
  float4 z = make_float4(0.f,0.f,0.f,0.f);
  float4* pm = (float4*)(out + (size_t)STEGO_N + (size_t)i*64);
#pragma unroll
  for(int j=0;j<16;j++) pm[j] = z;
  // LDS histogram, then PLAIN-STORE to this WG's private slot (no pre-zero needed)
  __syncthreads();
  atomicAdd(&h[binof(v)], 1u);
  __syncthreads();
  unsigned* slot = histp + (size_t)blockIdx.x*HISTB;
  for(int j=tid;j<HISTB;j+=256) slot[j] = h[j];
}

// ---------------- D2: reduce partials -> rank bins -> gather candidates ----------------
__global__ __launch_bounds__(1024) void k_mid(const double* __restrict__ var,
    const unsigned* __restrict__ histp, unsigned* __restrict__ cand_cnt,
    ull* __restrict__ cand, int* __restrict__ desc){
  __shared__ unsigned wsum[8];
  __shared__ int sdesc[3];                  // b0, b1, Cb (count below b0)
  int tid = threadIdx.x;
  int lane = tid & 63, wid = tid >> 6;
  if(tid < HISTB){
    // total count of bin 'tid' across the 384 per-WG partials (coalesced reads)
    unsigned part = 0;
#pragma unroll 8
    for(int w=0;w<NWG;w++) part += histp[(size_t)w*HISTB + tid];
    // wave-inclusive scan over the 512 bins (8 waves)
    unsigned incl = part;
#pragma unroll
    for(int off=1; off<64; off<<=1){
      unsigned t = __shfl_up(incl, off);
      if(lane >= off) incl += t;
    }
    if(lane==63) wsum[wid]=incl;
    __syncthreads();
    unsigned wpre=0;
#pragma unroll
    for(int w=0;w<8;w++) if(w<wid) wpre += wsum[w];
    unsigned c = wpre + incl - part;        // exclusive prefix of bin 'tid'
    if((unsigned)RANK0 >= c && (unsigned)RANK0 < c+part){ sdesc[0]=tid; sdesc[2]=(int)c; }
    if((unsigned)RANK1 >= c && (unsigned)RANK1 < c+part){ sdesc[1]=tid; }
  } else {
    __syncthreads();
  }
  __syncthreads();
  int b0=sdesc[0], b1=sdesc[1];
  if(blockIdx.x==0 && tid==0){ desc[0]=b0; desc[1]=b1; desc[2]=sdesc[2]; }
  // gather candidates from this WG's slice (order-independent set of bit-patterns)
  int i = blockIdx.x*1024 + tid;
  double v = var[i];
  int bn = binof(v);
  if(bn >= b0 && bn <= b1){
    unsigned idx = atomicAdd(cand_cnt, 1u);
    if(idx < CCAP) cand[idx] = (ull)__double_as_longlong(v);
  }
}

// ---------------- D3: exact rank select -> thr -> ballot queue -> embed ----------------
__global__ __launch_bounds__(1024) void k_final(const float* __restrict__ cover,
    const int* __restrict__ secret, const double* __restrict__ var,
    const int* __restrict__ desc, const unsigned* __restrict__ cand_cnt,
    const ull* __restrict__ gcand, float* __restrict__ out){
  __shared__ ull scand[CCAP];               // 32 KB
  __shared__ int queue[ELIG];
  __shared__ unsigned wcnt[16];
  __shared__ double sAB[2];
  int tid = threadIdx.x;
  int lane = tid & 63, wid = tid >> 6;
  unsigned Ku = *cand_cnt;
  int K = (Ku < (unsigned)CCAP) ? (int)Ku : CCAP;
  for(int t=tid;t<K;t+=1024) scand[t]=gcand[t];
  int Cb = desc[2];
  __syncthreads();
  // exact rank select among candidates (ties handled; order-independent)
  int r0 = RANK0 - Cb, r1 = RANK1 - Cb;
  for(int t=tid; t<K; t+=1024){
    ull x = scand[t];
    int cl=0, ce=0;
    for(int j=0;j<K;j++){ ull y=scand[j]; cl += (y<x); ce += (y==x); }
    if(cl<=r0 && r0<cl+ce) sAB[0]=__longlong_as_double((long long)x);
    if(cl<=r1 && r1<cl+ce) sAB[1]=__longlong_as_double((long long)x);
  }
  __syncthreads();
  double A=sAB[0], Bv=sAB[1];
  double thr = A + 0.9*(Bv - A);   // selection: var_norm>thr <=> var>thr_raw

  // chunked ballot scan in index order; stop once ELIG blocks queued
  int total = 0;
  for(int chunk=0; chunk<96; chunk++){
    int ii = chunk*1024 + tid;
    int f = (var[ii] > thr) ? 1 : 0;
    ull bal = __ballot(f);
    if(lane==0) wcnt[wid] = (unsigned)__popcll(bal);
    __syncthreads();
    int wpre=0, csum=0;
#pragma unroll
    for(int w=0;w<16;w++){
      int cc = (int)wcnt[w];
      if(w<wid) wpre += cc;
      csum += cc;
    }
    int P = total + wpre + (int)__popcll(bal & ((1ULL<<lane)-1ULL));
    if(f && P < ELIG) queue[P] = ii;
    total += csum;
    __syncthreads();
    if(total >= ELIG) break;
  }
  int nq = (total < ELIG) ? total : ELIG;

  // 16-wave shuffle-DCT fp64 embed: lane l owns coefficient/pixel (l>>3, l&7)
  int lr = lane>>3, lc = lane&7;
  for(int q = wid; q < nq; q += 16){
    int bi = queue[q], S2 = q;
    int m = bi & 63, n = (bi>>6)&63, bc = bi>>12, bb = bi / NPB;
    const float* p  = cover + ((size_t)bc*HW + (size_t)n*8)*HW + (size_t)m*8;
    float*       po = out   + ((size_t)bc*HW + (size_t)n*8)*HW + (size_t)m*8;
    double x = (double)p[(size_t)lr*HW + lc];     // X[lr][lc]
    // stage1: T1[r][v] = sum_j X[r][j]*D[v][j]
    double t1 = 0.0;
#pragma unroll
    for(int j=0;j<8;j++) t1 += __shfl(x, lr*8+j) * DT.d[lc][j];
    // stage2: C[u][v] = sum_k D[u][k]*T1[k][v]
    double coef = 0.0;
#pragma unroll
    for(int k=0;k<8;k++) coef += DT.d[lr][k] * __shfl(t1, k*8+lc);
    // embedding
    bool sel = (FMASK>>lane)&1ULL;
    float mv = 0.f;
    if(sel){
      int fp  = (int)__popcll(FMASK & ((1ULL<<lane)-1ULL));
      int ord = 37*S2 + fp;
      if(ord < NUMBITS){
        mv = 1.f;
        double rnd = rint(coef);                  // round half-to-even == jnp.round
        int lsb = ((int)fabs(rnd)) & 1;
        int bit = secret[(size_t)bb*NUMBITS + ord];
        if(lsb != bit) coef += ((coef>=0.0)?1.0:-1.0)*(2.0*(double)bit-1.0)*0.5;
      }
    }
    out[(size_t)STEGO_N + (size_t)bi*64 + lane] = mv;
    // inv stage1: T2[r][v] = sum_u D[u][r]*M[u][v]
    double t2 = 0.0;
#pragma unroll
    for(int u=0;u<8;u++) t2 += DT.d[u][lr] * __shfl(coef, u*8+lc);
    // inv stage2: pix[r][k] = sum_q T2[r][q]*D[q][k]
    double px = 0.0;
#pragma unroll
    for(int qq=0;qq<8;qq++) px += __shfl(t2, lr*8+qq) * DT.d[qq][lc];
    po[(size_t)lr*HW + lc] = (float)px;
  }
}

// ---------------- host launch ----------------
extern "C" void kernel_launch(void* const* d_in, const int* in_sizes, int n_in,
                              void* d_out, int out_size, void* d_ws, size_t ws_size,
                              hipStream_t stream) {
  const float* cover  = (const float*)d_in[0];
  const int*   secret = (const int*)d_in[1];
  float* out = (float*)d_out;
  char*  ws  = (char*)d_ws;

  // ws layout (bytes)
  double*   var      = (double*)(ws);             // 98304*8       = 786432
  unsigned* histp    = (unsigned*)(ws + 786432);  // 384*512*4     -> 1572864
  unsigned* cand_cnt = (unsigned*)(ws + 1572864); // 4 (pad 16)    -> 1572880
  int*      desc     = (int*)(ws + 1572880);      // 3 ints (pad)  -> 1572912
  ull*      cand     = (ull*)(ws + 1572912);      // 4096*8        -> 1605680

  k_stats<<<NWG,       256,  0, stream>>>(cover, out, var, histp, cand_cnt);
  k_mid  <<<NBLK/1024, 1024, 0, stream>>>(var, histp, cand_cnt, cand, desc);
  k_final<<<1,         1024, 0, stream>>>(cover, secret, var, desc, cand_cnt, cand, out);
}

// Round 10
// 89.158 us; speedup vs baseline: 2.2275x; 2.2275x over previous
//
#include <hip/hip_runtime.h>

// ---------------- problem constants ----------------
#define NBLK   98304     // 8*3*64*64 total 8x8 blocks
#define NPB    12288     // blocks per batch (3*64*64)
#define HW     512
#define NUMBITS 4096
#define RANK0  29490     // floor(0.3*(NBLK-1))
#define RANK1  29491
#define STEGO_N 6291456  // 8*3*512*512
#define ELIG   111       // ceil(4096/37) blocks contain eligible coefficients
#define HISTB  512       // fixed bins over variance range [0, 0.25]
#define CCAP   8192
#define NWG    384       // k_stats workgroups

typedef unsigned long long ull;

// ---------------- DCT matrix as compile-time constants ----------------
struct DTab { double d[8][8]; };

constexpr double CT_[9] = {
  1.0,
  0.98078528040323044913,
  0.92387953251128675613,
  0.83146961230254523708,
  0.70710678118654752440,
  0.55557023301960222474,
  0.38268343236508977173,
  0.19509032201612826785,
  0.0
};
constexpr double cospi16(int m){           // cos(pi*m/16), m >= 0
  int r = m % 32;
  return (r<=8) ? CT_[r] : (r<=16) ? -CT_[16-r] : (r<=24) ? -CT_[r-16] : CT_[32-r];
}
constexpr DTab make_dtab(){
  DTab t{};
  for(int k=0;k<8;k++) for(int n=0;n<8;n++){
    double s = (k==0) ? 0.35355339059327376220 : 0.5; // sqrt(1/8), sqrt(2/8)
    t.d[k][n] = s * cospi16((2*n+1)*k);
  }
  return t;
}
constexpr DTab DT = make_dtab();

constexpr ull make_fmask(){ // bit u*8+v set iff 3 <= u+v <= 8
  ull m = 0;
  for(int u=0;u<8;u++) for(int v=0;v<8;v++){
    int s=u+v; if(s>=3 && s<=8) m |= (1ULL << (u*8+v));
  }
  return m;
}
constexpr ull FMASK = make_fmask();  // 37 bits set

__device__ __forceinline__ int binof(double v){
  int b = (int)(v * 2048.0);                // HISTB/0.25 — fixed, deterministic
  if(b > HISTB-1) b = HISTB-1;
  return b;                                 // v >= 0 always
}

// ---------------- D1: copy + map-zero + variance + per-WG histogram ----------------
__global__ __launch_bounds__(256) void k_stats(const float* __restrict__ cover,
    float* __restrict__ out, double* __restrict__ var,
    unsigned* __restrict__ histp, unsigned* __restrict__ cand_cnt){
  __shared__ unsigned h[HISTB];             // 2 KB
  int tid = threadIdx.x;
  int i = blockIdx.x*256 + tid;             // block id over (b,c,n,m)
  for(int j=tid;j<HISTB;j+=256) h[j]=0u;
  if(blockIdx.x==0 && tid==0) *cand_cnt = 0u;
  int m = i & 63, n = (i>>6)&63, bc = i>>12;
  const float* p  = cover + ((size_t)bc*HW + (size_t)n*8)*HW + (size_t)m*8;
  float*       po = out   + ((size_t)bc*HW + (size_t)n*8)*HW + (size_t)m*8;
  double s1=0.0, s2=0.0;
#pragma unroll
  for(int r=0;r<8;r++){
    const float4* q = (const float4*)(p + (size_t)r*HW);
    float4 a = q[0], b = q[1];
    float4* w = (float4*)(po + (size_t)r*HW);
    w[0]=a; w[1]=b;
    double x;
    x=(double)a.x; s1+=x; s2+=x*x;
    x=(double)a.y; s1+=x; s2+=x*x;
    x=(double)a.z; s1+=x; s2+=x*x;
    x=(double)a.w; s1+=x; s2+=x*x;
    x=(double)b.x; s1+=x; s2+=x*x;
    x=(double)b.y; s1+=x; s2+=x*x;
    x=(double)b.z; s1+=x; s2+=x*x;
    x=(double)b.w; s1+=x; s2+=x*x;
  }
  double mean = s1*(1.0/64.0);
  double v = s2*(1.0/64.0) - mean*mean;
  if(v < 0.0) v = 0.0;
  var[i] = v;
  // zero this block's embedding map (fixed up later for eligible blocks)
  float4 z = make_float4(0.f,0.f,0.f,0.f);
  float4* pm = (float4*)(out + (size_t)STEGO_N + (size_t)i*64);
#pragma unroll
  for(int j=0;j<16;j++) pm[j] = z;
  // LDS histogram, then PLAIN-STORE to this WG's private slot (no pre-zero needed)
  __syncthreads();
  atomicAdd(&h[binof(v)], 1u);
  __syncthreads();
  unsigned* slot = histp + (size_t)blockIdx.x*HISTB;
  for(int j=tid;j<HISTB;j+=256) slot[j] = h[j];
}

// ---------------- D2: reduce partials -> rank bins -> gather candidates ----------------
__global__ __launch_bounds__(1024) void k_mid(const double* __restrict__ var,
    const unsigned* __restrict__ histp, unsigned* __restrict__ cand_cnt,
    ull* __restrict__ cand, int* __restrict__ desc){
  __shared__ unsigned wsum[8];
  __shared__ int sdesc[3];                  // b0, b1, Cb (count below b0)
  int tid = threadIdx.x;
  int lane = tid & 63, wid = tid >> 6;
  if(tid < HISTB){
    // total count of bin 'tid' across the 384 per-WG partials (coalesced reads)
    unsigned part = 0;
#pragma unroll 8
    for(int w=0;w<NWG;w++) part += histp[(size_t)w*HISTB + tid];
    // wave-inclusive scan over the 512 bins (8 waves)
    unsigned incl = part;
#pragma unroll
    for(int off=1; off<64; off<<=1){
      unsigned t = __shfl_up(incl, off);
      if(lane >= off) incl += t;
    }
    if(lane==63) wsum[wid]=incl;
    __syncthreads();
    unsigned wpre=0;
#pragma unroll
    for(int w=0;w<8;w++) if(w<wid) wpre += wsum[w];
    unsigned c = wpre + incl - part;        // exclusive prefix of bin 'tid'
    if((unsigned)RANK0 >= c && (unsigned)RANK0 < c+part){ sdesc[0]=tid; sdesc[2]=(int)c; }
    if((unsigned)RANK1 >= c && (unsigned)RANK1 < c+part){ sdesc[1]=tid; }
  } else {
    __syncthreads();
  }
  __syncthreads();
  int b0=sdesc[0], b1=sdesc[1];
  if(blockIdx.x==0 && tid==0){ desc[0]=b0; desc[1]=b1; desc[2]=sdesc[2]; }
  // gather candidates from this WG's slice (order-independent set of bit-patterns)
  int i = blockIdx.x*1024 + tid;
  double v = var[i];
  int bn = binof(v);
  if(bn >= b0 && bn <= b1){
    unsigned idx = atomicAdd(cand_cnt, 1u);
    if(idx < CCAP) cand[idx] = (ull)__double_as_longlong(v);
  }
}

// ---------------- D3: O(K) radix select -> thr -> ballot queue -> embed ----------------
__global__ __launch_bounds__(1024) void k_final(const float* __restrict__ cover,
    const int* __restrict__ secret, const double* __restrict__ var,
    const int* __restrict__ desc, const unsigned* __restrict__ cand_cnt,
    const ull* __restrict__ gcand, float* __restrict__ out){
  __shared__ ull scand[CCAP];               // 64 KB
  __shared__ unsigned hist[2048];           // 8 KB
  __shared__ unsigned wsum[16];
  __shared__ int spick[2];                  // chosen digit, count-below-digit
  __shared__ unsigned s_cnt;
  __shared__ ull s_min;
  __shared__ int queue[ELIG];
  __shared__ unsigned wcnt[16];
  int tid = threadIdx.x;
  int lane = tid & 63, wid = tid >> 6;
  unsigned Ku = *cand_cnt;
  int K = (Ku < (unsigned)CCAP) ? (int)Ku : CCAP;
  for(int t=tid;t<K;t+=1024) scand[t]=gcand[t];
  int Cb = desc[2];
  if(tid==0){ s_cnt=0u; s_min=~0ULL; }
  __syncthreads();

  // ---- radix select: A = rank r0 among the K candidate bit-patterns ----
  int r0 = RANK0 - Cb;
  const int sh[6] = {55,44,33,22,11,0};
  ull pref = 0ULL;
  int rk = r0;
  for(int r=0;r<6;r++){
    for(int j=tid;j<2048;j+=1024) hist[j]=0u;
    __syncthreads();
    for(int t=tid;t<K;t+=1024){
      ull x = scand[t];
      bool match = (r==0) || ((x>>sh[r-1]) == (pref>>sh[r-1]));
      if(match) atomicAdd(&hist[(unsigned)((x>>sh[r]) & 2047ULL)], 1u);
    }
    __syncthreads();
    unsigned a0 = hist[2*tid], a1 = hist[2*tid+1], part = a0+a1;
    unsigned incl = part;
#pragma unroll
    for(int off=1; off<64; off<<=1){
      unsigned t = __shfl_up(incl, off);
      if(lane >= off) incl += t;
    }
    if(lane==63) wsum[wid]=incl;
    __syncthreads();
    unsigned wpre=0;
#pragma unroll
    for(int w=0;w<16;w++) if(w<wid) wpre += wsum[w];
    incl += wpre;
    unsigned excl = incl - part;
    if((unsigned)rk >= excl && (unsigned)rk < incl){
      if((unsigned)rk < excl + a0){ spick[0]=2*tid;   spick[1]=(int)excl; }
      else                        { spick[0]=2*tid+1; spick[1]=(int)(excl+a0); }
    }
    __syncthreads();
    pref |= ((ull)spick[0]) << sh[r];
    rk   -= spick[1];
    __syncthreads();                        // protect spick/hist before next round
  }

  // ---- B = rank r0+1: A if (#<=A) >= r0+2, else min{x > A} ----
  {
    unsigned myle = 0; ull mymin = ~0ULL;
    for(int t=tid;t<K;t+=1024){
      ull x = scand[t];
      if(x <= pref) myle++;
      else if(x < mymin) mymin = x;
    }
    if(myle) atomicAdd(&s_cnt, myle);
    atomicMin(&s_min, mymin);
    __syncthreads();
  }
  ull Bbits = (s_cnt >= (unsigned)(r0+2)) ? pref : s_min;
  double A  = __longlong_as_double((long long)pref);
  double Bv = __longlong_as_double((long long)Bbits);
  double thr = A + 0.9*(Bv - A);   // selection: var_norm>thr <=> var>thr_raw

  // ---- chunked ballot scan in index order; stop once ELIG blocks queued ----
  int total = 0;
  for(int chunk=0; chunk<96; chunk++){
    int ii = chunk*1024 + tid;
    int f = (var[ii] > thr) ? 1 : 0;
    ull bal = __ballot(f);
    if(lane==0) wcnt[wid] = (unsigned)__popcll(bal);
    __syncthreads();
    int wpre=0, csum=0;
#pragma unroll
    for(int w=0;w<16;w++){
      int cc = (int)wcnt[w];
      if(w<wid) wpre += cc;
      csum += cc;
    }
    int P = total + wpre + (int)__popcll(bal & ((1ULL<<lane)-1ULL));
    if(f && P < ELIG) queue[P] = ii;
    total += csum;
    __syncthreads();
    if(total >= ELIG) break;
  }
  int nq = (total < ELIG) ? total : ELIG;

  // ---- 16-wave shuffle-DCT fp64 embed: lane l owns coeff/pixel (l>>3, l&7) ----
  int lr = lane>>3, lc = lane&7;
  for(int q = wid; q < nq; q += 16){
    int bi = queue[q], S2 = q;
    int m = bi & 63, n = (bi>>6)&63, bc = bi>>12, bb = bi / NPB;
    const float* p  = cover + ((size_t)bc*HW + (size_t)n*8)*HW + (size_t)m*8;
    float*       po = out   + ((size_t)bc*HW + (size_t)n*8)*HW + (size_t)m*8;
    double x = (double)p[(size_t)lr*HW + lc];     // X[lr][lc]
    // stage1: T1[r][v] = sum_j X[r][j]*D[v][j]
    double t1 = 0.0;
#pragma unroll
    for(int j=0;j<8;j++) t1 += __shfl(x, lr*8+j) * DT.d[lc][j];
    // stage2: C[u][v] = sum_k D[u][k]*T1[k][v]
    double coef = 0.0;
#pragma unroll
    for(int k=0;k<8;k++) coef += DT.d[lr][k] * __shfl(t1, k*8+lc);
    // embedding
    bool sel = (FMASK>>lane)&1ULL;
    float mv = 0.f;
    if(sel){
      int fp  = (int)__popcll(FMASK & ((1ULL<<lane)-1ULL));
      int ord = 37*S2 + fp;
      if(ord < NUMBITS){
        mv = 1.f;
        double rnd = rint(coef);                  // round half-to-even == jnp.round
        int lsb = ((int)fabs(rnd)) & 1;
        int bit = secret[(size_t)bb*NUMBITS + ord];
        if(lsb != bit) coef += ((coef>=0.0)?1.0:-1.0)*(2.0*(double)bit-1.0)*0.5;
      }
    }
    out[(size_t)STEGO_N + (size_t)bi*64 + lane] = mv;
    // inv stage1: T2[r][v] = sum_u D[u][r]*M[u][v]
    double t2 = 0.0;
#pragma unroll
    for(int u=0;u<8;u++) t2 += DT.d[u][lr] * __shfl(coef, u*8+lc);
    // inv stage2: pix[r][k] = sum_q T2[r][q]*D[q][k]
    double px = 0.0;
#pragma unroll
    for(int qq=0;qq<8;qq++) px += __shfl(t2, lr*8+qq) * DT.d[qq][lc];
    po[(size_t)lr*HW + lc] = (float)px;
  }
}

// ---------------- host launch ----------------
extern "C" void kernel_launch(void* const* d_in, const int* in_sizes, int n_in,
                              void* d_out, int out_size, void* d_ws, size_t ws_size,
                              hipStream_t stream) {
  const float* cover  = (const float*)d_in[0];
  const int*   secret = (const int*)d_in[1];
  float* out = (float*)d_out;
  char*  ws  = (char*)d_ws;

  // ws layout (bytes)
  double*   var      = (double*)(ws);             // 98304*8       = 786432
  unsigned* histp    = (unsigned*)(ws + 786432);  // 384*512*4     -> 1572864
  unsigned* cand_cnt = (unsigned*)(ws + 1572864); // 4 (pad 16)    -> 1572880
  int*      desc     = (int*)(ws + 1572880);      // 3 ints (pad)  -> 1572912
  ull*      cand     = (ull*)(ws + 1572912);      // 8192*8        -> 1638448

  k_stats<<<NWG,       256,  0, stream>>>(cover, out, var, histp, cand_cnt);
  k_mid  <<<NBLK/1024, 1024, 0, stream>>>(var, histp, cand_cnt, cand, desc);
  k_final<<<1,         1024, 0, stream>>>(cover, secret, var, desc, cand_cnt, cand, out);
}

// Round 11
// 65.847 us; speedup vs baseline: 3.0160x; 1.3540x over previous
//
#include <hip/hip_runtime.h>

// ---------------- problem constants ----------------
#define NBLK   98304     // 8*3*64*64 total 8x8 blocks
#define NPB    12288     // blocks per batch (3*64*64)
#define HW     512
#define NUMBITS 4096
#define RANK0  29490     // floor(0.3*(NBLK-1)); sel <=> var > s[RANK0] (adjacent order stats)
#define STEGO_N 6291456  // 8*3*512*512
#define ELIG   111       // ceil(4096/37) blocks contain eligible coefficients
#define HISTB  512       // fixed bins over variance range [0, 0.25]
#define CCAP   4096      // LDS candidate cap (bin-b0 population ~500)
#define NWG    384       // k_stats workgroups

typedef unsigned long long ull;

// ---------------- DCT matrix as compile-time constants ----------------
struct DTab { double d[8][8]; };

constexpr double CT_[9] = {
  1.0,
  0.98078528040323044913,
  0.92387953251128675613,
  0.83146961230254523708,
  0.70710678118654752440,
  0.55557023301960222474,
  0.38268343236508977173,
  0.19509032201612826785,
  0.0
};
constexpr double cospi16(int m){           // cos(pi*m/16), m >= 0
  int r = m % 32;
  return (r<=8) ? CT_[r] : (r<=16) ? -CT_[16-r] : (r<=24) ? -CT_[r-16] : CT_[32-r];
}
constexpr DTab make_dtab(){
  DTab t{};
  for(int k=0;k<8;k++) for(int n=0;n<8;n++){
    double s = (k==0) ? 0.35355339059327376220 : 0.5; // sqrt(1/8), sqrt(2/8)
    t.d[k][n] = s * cospi16((2*n+1)*k);
  }
  return t;
}
constexpr DTab DT = make_dtab();

constexpr ull make_fmask(){ // bit u*8+v set iff 3 <= u+v <= 8
  ull m = 0;
  for(int u=0;u<8;u++) for(int v=0;v<8;v++){
    int s=u+v; if(s>=3 && s<=8) m |= (1ULL << (u*8+v));
  }
  return m;
}
constexpr ull FMASK = make_fmask();  // 37 bits set

__device__ __forceinline__ int binof(double v){
  int b = (int)(v * 2048.0);                // HISTB/0.25 — fixed, deterministic
  if(b > HISTB-1) b = HISTB-1;
  return b;                                 // v >= 0 always
}

// one WAVE embeds one block (global selected-rank S2); lane l owns coeff (l>>3,l&7)
__device__ __forceinline__ void embed_one(const float* __restrict__ cover,
    const int* __restrict__ secret, float* __restrict__ out, int bi, int S2, int lane){
  int lr = lane>>3, lc = lane&7;
  int m = bi & 63, n = (bi>>6)&63, bc = bi>>12, bb = bi / NPB;
  const float* p  = cover + ((size_t)bc*HW + (size_t)n*8)*HW + (size_t)m*8;
  float*       po = out   + ((size_t)bc*HW + (size_t)n*8)*HW + (size_t)m*8;
  double x = (double)p[(size_t)lr*HW + lc];     // X[lr][lc]
  // stage1: T1[r][v] = sum_j X[r][j]*D[v][j]
  double t1 = 0.0;
#pragma unroll
  for(int j=0;j<8;j++) t1 += __shfl(x, lr*8+j) * DT.d[lc][j];
  // stage2: C[u][v] = sum_k D[u][k]*T1[k][v]
  double coef = 0.0;
#pragma unroll
  for(int k=0;k<8;k++) coef += DT.d[lr][k] * __shfl(t1, k*8+lc);
  // embedding
  bool sel = (FMASK>>lane)&1ULL;
  float mv = 0.f;
  if(sel){
    int fp  = (int)__popcll(FMASK & ((1ULL<<lane)-1ULL));
    int ord = 37*S2 + fp;
    if(ord < NUMBITS){
      mv = 1.f;
      double rnd = rint(coef);                  // round half-to-even == jnp.round
      int lsb = ((int)fabs(rnd)) & 1;
      int bit = secret[(size_t)bb*NUMBITS + ord];
      if(lsb != bit) coef += ((coef>=0.0)?1.0:-1.0)*(2.0*(double)bit-1.0)*0.5;
    }
  }
  out[(size_t)STEGO_N + (size_t)bi*64 + lane] = mv;
  // inv stage1: T2[r][v] = sum_u D[u][r]*M[u][v]
  double t2 = 0.0;
#pragma unroll
  for(int u=0;u<8;u++) t2 += DT.d[u][lr] * __shfl(coef, u*8+lc);
  // inv stage2: pix[r][k] = sum_q T2[r][q]*D[q][k]
  double px = 0.0;
#pragma unroll
  for(int qq=0;qq<8;qq++) px += __shfl(t2, lr*8+qq) * DT.d[qq][lc];
  po[(size_t)lr*HW + lc] = (float)px;
}

// ---------------- D1: copy + map-zero + variance + per-WG partial histogram ----------------
__global__ __launch_bounds__(256) void k_stats(const float* __restrict__ cover,
    float* __restrict__ out, double* __restrict__ var,
    unsigned* __restrict__ histp){
  __shared__ unsigned h[HISTB];             // 2 KB
  int tid = threadIdx.x;
  int i = blockIdx.x*256 + tid;             // block id over (b,c,n,m)
  for(int j=tid;j<HISTB;j+=256) h[j]=0u;
  int m = i & 63, n = (i>>6)&63, bc = i>>12;
  const float* p  = cover + ((size_t)bc*HW + (size_t)n*8)*HW + (size_t)m*8;
  float*       po = out   + ((size_t)bc*HW + (size_t)n*8)*HW + (size_t)m*8;
  double s1=0.0, s2=0.0;
#pragma unroll
  for(int r=0;r<8;r++){
    const float4* q = (const float4*)(p + (size_t)r*HW);
    float4 a = q[0], b = q[1];
    float4* w = (float4*)(po + (size_t)r*HW);
    w[0]=a; w[1]=b;
    double x;
    x=(double)a.x; s1+=x; s2+=x*x;
    x=(double)a.y; s1+=x; s2+=x*x;
    x=(double)a.z; s1+=x; s2+=x*x;
    x=(double)a.w; s1+=x; s2+=x*x;
    x=(double)b.x; s1+=x; s2+=x*x;
    x=(double)b.y; s1+=x; s2+=x*x;
    x=(double)b.z; s1+=x; s2+=x*x;
    x=(double)b.w; s1+=x; s2+=x*x;
  }
  double mean = s1*(1.0/64.0);
  double v = s2*(1.0/64.0) - mean*mean;
  if(v < 0.0) v = 0.0;
  var[i] = v;
  // zero this block's embedding map (fixed up later for eligible blocks)
  float4 z = make_float4(0.f,0.f,0.f,0.f);
  float4* pm = (float4*)(out + (size_t)STEGO_N + (size_t)i*64);
#pragma unroll
  for(int j=0;j<16;j++) pm[j] = z;
  // LDS histogram, then PLAIN-STORE to this WG's private slot (no pre-zero needed)
  __syncthreads();
  atomicAdd(&h[binof(v)], 1u);
  __syncthreads();
  unsigned* slot = histp + (size_t)blockIdx.x*HISTB;
  for(int j=tid;j<HISTB;j+=256) slot[j] = h[j];
}

// ---------------- D2: everything else, 96 WGs, zero cross-WG coupling ----------------
__global__ __launch_bounds__(1024) void k_big(const float* __restrict__ cover,
    const int* __restrict__ secret, const double* __restrict__ var,
    const unsigned* __restrict__ histp, float* __restrict__ out){
  __shared__ ull cand[CCAP];                // 32 KB
  __shared__ unsigned hist[2048];           // 8 KB (radix rounds)
  __shared__ unsigned wsum[16];
  __shared__ int sdesc[2];                  // b0, Cb (count below b0)
  __shared__ int spick[2];
  __shared__ unsigned s_ccnt;
  __shared__ int queue[ELIG];
  __shared__ unsigned wcnt[16];
  int tid = threadIdx.x;
  int lane = tid & 63, wid = tid >> 6, g = blockIdx.x;
  if(tid==0) s_ccnt = 0u;

  // ---- A: reduce 384 partials -> bin totals -> locate b0, Cb (redundant per WG) ----
  unsigned part = 0, incl = 0;
  if(tid < HISTB){
#pragma unroll 8
    for(int w=0;w<NWG;w++) part += histp[(size_t)w*HISTB + tid];
    incl = part;
#pragma unroll
    for(int off=1; off<64; off<<=1){
      unsigned t = __shfl_up(incl, off);
      if(lane >= off) incl += t;
    }
    if(lane==63) wsum[wid]=incl;
  }
  __syncthreads();
  if(tid < HISTB){
    unsigned wpre=0;
#pragma unroll
    for(int w=0;w<8;w++) if(w<wid) wpre += wsum[w];
    unsigned c = wpre + incl - part;        // exclusive prefix of bin 'tid'
    if((unsigned)RANK0 >= c && (unsigned)RANK0 < c+part){ sdesc[0]=tid; sdesc[1]=(int)c; }
  }
  __syncthreads();
  int b0 = sdesc[0], Cb = sdesc[1];

  // ---- B: sweep full var, gather bin-b0 values into LDS (set is deterministic) ----
  const double4* v4 = (const double4*)var;  // 24576 double4
  for(int j=tid; j<24576; j+=1024){
    double4 v = v4[j];
    double vv[4] = {v.x, v.y, v.z, v.w};
#pragma unroll
    for(int e=0;e<4;e++){
      if(binof(vv[e]) == b0){
        unsigned idx = atomicAdd(&s_ccnt, 1u);
        if(idx < CCAP) cand[idx] = (ull)__double_as_longlong(vv[e]);
      }
    }
  }
  __syncthreads();
  int K = (s_ccnt < (unsigned)CCAP) ? (int)s_ccnt : CCAP;

  // ---- C: radix select rank (RANK0-Cb) among K candidates -> A bits ----
  int rk = RANK0 - Cb;
  const int sh[6] = {55,44,33,22,11,0};
  ull pref = 0ULL;
  for(int r=0;r<6;r++){
    for(int j=tid;j<2048;j+=1024) hist[j]=0u;
    __syncthreads();
    for(int t=tid;t<K;t+=1024){
      ull x = cand[t];
      bool match = (r==0) || ((x>>sh[r-1]) == (pref>>sh[r-1]));
      if(match) atomicAdd(&hist[(unsigned)((x>>sh[r]) & 2047ULL)], 1u);
    }
    __syncthreads();
    unsigned a0 = hist[2*tid], a1 = hist[2*tid+1], p2 = a0+a1;
    unsigned inc2 = p2;
#pragma unroll
    for(int off=1; off<64; off<<=1){
      unsigned t = __shfl_up(inc2, off);
      if(lane >= off) inc2 += t;
    }
    if(lane==63) wsum[wid]=inc2;
    __syncthreads();
    unsigned wpre=0;
#pragma unroll
    for(int w=0;w<16;w++) if(w<wid) wpre += wsum[w];
    inc2 += wpre;
    unsigned excl = inc2 - p2;
    if((unsigned)rk >= excl && (unsigned)rk < inc2){
      if((unsigned)rk < excl + a0){ spick[0]=2*tid;   spick[1]=(int)excl; }
      else                        { spick[0]=2*tid+1; spick[1]=(int)(excl+a0); }
    }
    __syncthreads();
    pref |= ((ull)spick[0]) << sh[r];
    rk   -= spick[1];
    __syncthreads();
  }
  double A = __longlong_as_double((long long)pref);  // sel <=> var > A

  // ---- D: chunk-0 ballot -> queue; distributed one-wave-per-block embed ----
  {
    int f = (var[tid] > A) ? 1 : 0;         // block id == tid (chunk 0)
    ull bal = __ballot(f);
    if(lane==0) wcnt[wid] = (unsigned)__popcll(bal);
    __syncthreads();
    int wpre=0, csum=0;
#pragma unroll
    for(int w=0;w<16;w++){
      int cc = (int)wcnt[w];
      if(w<wid) wpre += cc;
      csum += cc;
    }
    int P = wpre + (int)__popcll(bal & ((1ULL<<lane)-1ULL));
    if(f && P < ELIG) queue[P] = tid;
    __syncthreads();
    if(csum >= ELIG){
      // common path: first ELIG selected blocks all lie in chunk 0
      int W = g*16 + wid;                   // global wave id in [0,1536)
      if(W < ELIG) embed_one(cover, secret, out, queue[W], W, lane);
      return;
    }
  }

  // ---- rare fallback: WG0 alone runs the full chunked scan + 16-wave embed ----
  if(g != 0) return;
  __syncthreads();
  int total = 0;
  for(int chunk=0; chunk<96; chunk++){
    int ii = chunk*1024 + tid;
    int f = (var[ii] > A) ? 1 : 0;
    ull bal = __ballot(f);
    if(lane==0) wcnt[wid] = (unsigned)__popcll(bal);
    __syncthreads();
    int wpre=0, csum=0;
#pragma unroll
    for(int w=0;w<16;w++){
      int cc = (int)wcnt[w];
      if(w<wid) wpre += cc;
      csum += cc;
    }
    int P = total + wpre + (int)__popcll(bal & ((1ULL<<lane)-1ULL));
    if(f && P < ELIG) queue[P] = ii;
    total += csum;
    __syncthreads();
    if(total >= ELIG) break;
  }
  int nq = (total < ELIG) ? total : ELIG;
  for(int q = wid; q < nq; q += 16)
    embed_one(cover, secret, out, queue[q], q, lane);
}

// ---------------- host launch ----------------
extern "C" void kernel_launch(void* const* d_in, const int* in_sizes, int n_in,
                              void* d_out, int out_size, void* d_ws, size_t ws_size,
                              hipStream_t stream) {
  const float* cover  = (const float*)d_in[0];
  const int*   secret = (const int*)d_in[1];
  float* out = (float*)d_out;
  char*  ws  = (char*)d_ws;

  // ws layout (bytes)
  double*   var   = (double*)(ws);                // 98304*8   = 786432
  unsigned* histp = (unsigned*)(ws + 786432);     // 384*512*4 -> 1572864

  k_stats<<<NWG, 256,  0, stream>>>(cover, out, var, histp);
  k_big  <<<96,  1024, 0, stream>>>(cover, secret, var, histp, out);
}

// Round 12
// 61.547 us; speedup vs baseline: 3.2268x; 1.0699x over previous
//
#include <hip/hip_runtime.h>

// ---------------- problem constants ----------------
#define NBLK   98304     // 8*3*64*64 total 8x8 blocks
#define NPB    12288     // blocks per batch (3*64*64)
#define HW     512
#define NUMBITS 4096
#define RANK0  29490     // floor(0.3*(NBLK-1)); sel <=> var > s[RANK0] (adjacent order stats)
#define STEGO_N 6291456  // 8*3*512*512
#define ELIG   111       // ceil(4096/37) blocks contain eligible coefficients
#define HISTB  512       // fixed bins over variance range [0, 0.25]
#define CCAP   4096      // candidate cap (bin-b0 population ~500)
#define NWGS   96        // workgroups in each kernel (1024 thr, 1 block/thread)

typedef unsigned long long ull;

// ---------------- DCT matrix as compile-time constants ----------------
struct DTab { double d[8][8]; };

constexpr double CT_[9] = {
  1.0,
  0.98078528040323044913,
  0.92387953251128675613,
  0.83146961230254523708,
  0.70710678118654752440,
  0.55557023301960222474,
  0.38268343236508977173,
  0.19509032201612826785,
  0.0
};
constexpr double cospi16(int m){           // cos(pi*m/16), m >= 0
  int r = m % 32;
  return (r<=8) ? CT_[r] : (r<=16) ? -CT_[16-r] : (r<=24) ? -CT_[r-16] : CT_[32-r];
}
constexpr DTab make_dtab(){
  DTab t{};
  for(int k=0;k<8;k++) for(int n=0;n<8;n++){
    double s = (k==0) ? 0.35355339059327376220 : 0.5; // sqrt(1/8), sqrt(2/8)
    t.d[k][n] = s * cospi16((2*n+1)*k);
  }
  return t;
}
constexpr DTab DT = make_dtab();

constexpr ull make_fmask(){ // bit u*8+v set iff 3 <= u+v <= 8
  ull m = 0;
  for(int u=0;u<8;u++) for(int v=0;v<8;v++){
    int s=u+v; if(s>=3 && s<=8) m |= (1ULL << (u*8+v));
  }
  return m;
}
constexpr ull FMASK = make_fmask();  // 37 bits set

__device__ __forceinline__ int binof(double v){
  int b = (int)(v * 2048.0);                // HISTB/0.25 — fixed, deterministic
  if(b > HISTB-1) b = HISTB-1;
  return b;                                 // v >= 0 always
}

// one WAVE embeds one block (global selected-rank S2); lane l owns coeff (l>>3,l&7)
__device__ __forceinline__ void embed_one(const float* __restrict__ cover,
    const int* __restrict__ secret, float* __restrict__ out, int bi, int S2, int lane){
  int lr = lane>>3, lc = lane&7;
  int m = bi & 63, n = (bi>>6)&63, bc = bi>>12, bb = bi / NPB;
  const float* p  = cover + ((size_t)bc*HW + (size_t)n*8)*HW + (size_t)m*8;
  float*       po = out   + ((size_t)bc*HW + (size_t)n*8)*HW + (size_t)m*8;
  double x = (double)p[(size_t)lr*HW + lc];     // X[lr][lc]
  // stage1: T1[r][v] = sum_j X[r][j]*D[v][j]
  double t1 = 0.0;
#pragma unroll
  for(int j=0;j<8;j++) t1 += __shfl(x, lr*8+j) * DT.d[lc][j];
  // stage2: C[u][v] = sum_k D[u][k]*T1[k][v]
  double coef = 0.0;
#pragma unroll
  for(int k=0;k<8;k++) coef += DT.d[lr][k] * __shfl(t1, k*8+lc);
  // embedding
  bool sel = (FMASK>>lane)&1ULL;
  float mv = 0.f;
  if(sel){
    int fp  = (int)__popcll(FMASK & ((1ULL<<lane)-1ULL));
    int ord = 37*S2 + fp;
    if(ord < NUMBITS){
      mv = 1.f;
      double rnd = rint(coef);                  // round half-to-even == jnp.round
      int lsb = ((int)fabs(rnd)) & 1;
      int bit = secret[(size_t)bb*NUMBITS + ord];
      if(lsb != bit) coef += ((coef>=0.0)?1.0:-1.0)*(2.0*(double)bit-1.0)*0.5;
    }
  }
  out[(size_t)STEGO_N + (size_t)bi*64 + lane] = mv;
  // inv stage1: T2[r][v] = sum_u D[u][r]*M[u][v]
  double t2 = 0.0;
#pragma unroll
  for(int u=0;u<8;u++) t2 += DT.d[u][lr] * __shfl(coef, u*8+lc);
  // inv stage2: pix[r][k] = sum_q T2[r][q]*D[q][k]
  double px = 0.0;
#pragma unroll
  for(int qq=0;qq<8;qq++) px += __shfl(t2, lr*8+qq) * DT.d[qq][lc];
  po[(size_t)lr*HW + lc] = (float)px;
}

// ---------------- D1: copy + map-zero + variance + transposed ushort hist ----------------
__global__ __launch_bounds__(1024) void k_stats(const float* __restrict__ cover,
    float* __restrict__ out, double* __restrict__ var,
    unsigned short* __restrict__ histp16, unsigned* __restrict__ cand_cnt){
  __shared__ unsigned h[HISTB];             // 2 KB
  int tid = threadIdx.x, g = blockIdx.x;
  int i = g*1024 + tid;                     // block id over (b,c,n,m)
  if(tid < HISTB) h[tid]=0u;
  if(g==0 && tid==0) *cand_cnt = 0u;
  int m = i & 63, n = (i>>6)&63, bc = i>>12;
  const float* p  = cover + ((size_t)bc*HW + (size_t)n*8)*HW + (size_t)m*8;
  float*       po = out   + ((size_t)bc*HW + (size_t)n*8)*HW + (size_t)m*8;
  double s1=0.0, s2=0.0;
#pragma unroll
  for(int r=0;r<8;r++){
    const float4* q = (const float4*)(p + (size_t)r*HW);
    float4 a = q[0], b = q[1];
    float4* w = (float4*)(po + (size_t)r*HW);
    w[0]=a; w[1]=b;
    double x;
    x=(double)a.x; s1+=x; s2+=x*x;
    x=(double)a.y; s1+=x; s2+=x*x;
    x=(double)a.z; s1+=x; s2+=x*x;
    x=(double)a.w; s1+=x; s2+=x*x;
    x=(double)b.x; s1+=x; s2+=x*x;
    x=(double)b.y; s1+=x; s2+=x*x;
    x=(double)b.z; s1+=x; s2+=x*x;
    x=(double)b.w; s1+=x; s2+=x*x;
  }
  double mean = s1*(1.0/64.0);
  double v = s2*(1.0/64.0) - mean*mean;
  if(v < 0.0) v = 0.0;
  var[i] = v;
  // zero this block's embedding map (fixed up later for eligible blocks)
  float4 z = make_float4(0.f,0.f,0.f,0.f);
  float4* pm = (float4*)(out + (size_t)STEGO_N + (size_t)i*64);
#pragma unroll
  for(int j=0;j<16;j++) pm[j] = z;
  // per-WG LDS histogram -> transposed ushort slot (row = bin, col = WG)
  __syncthreads();
  atomicAdd(&h[binof(v)], 1u);
  __syncthreads();
  if(tid < HISTB) histp16[(size_t)tid*NWGS + g] = (unsigned short)h[tid];
}

// ---------------- D2: vector-reduce hist -> b0/Cb -> own-slice candidate gather ----------------
__global__ __launch_bounds__(1024) void k_mid(const double* __restrict__ var,
    const unsigned short* __restrict__ histp16, unsigned* __restrict__ cand_cnt,
    ull* __restrict__ cand, int* __restrict__ desc){
  __shared__ unsigned wsum[8];
  __shared__ int sdesc[2];                  // b0, Cb (count below b0)
  int tid = threadIdx.x, g = blockIdx.x;
  int lane = tid & 63, wid = tid >> 6;
  unsigned part = 0, incl = 0;
  if(tid < HISTB){
    // sum this bin's row: 96 ushorts = 12 x uint4 (rows are 192 B, 16B-aligned)
    const uint4* row = (const uint4*)(histp16 + (size_t)tid*NWGS);
#pragma unroll
    for(int j=0;j<12;j++){
      uint4 w = row[j];
      part += (w.x&0xFFFFu)+(w.x>>16)+(w.y&0xFFFFu)+(w.y>>16)
            + (w.z&0xFFFFu)+(w.z>>16)+(w.w&0xFFFFu)+(w.w>>16);
    }
    incl = part;
#pragma unroll
    for(int off=1; off<64; off<<=1){
      unsigned t = __shfl_up(incl, off);
      if(lane >= off) incl += t;
    }
    if(lane==63) wsum[wid]=incl;
  }
  __syncthreads();
  if(tid < HISTB){
    unsigned wpre=0;
#pragma unroll
    for(int w=0;w<8;w++) if(w<wid) wpre += wsum[w];
    unsigned c = wpre + incl - part;        // exclusive prefix of bin 'tid'
    if((unsigned)RANK0 >= c && (unsigned)RANK0 < c+part){ sdesc[0]=tid; sdesc[1]=(int)c; }
  }
  __syncthreads();
  int b0 = sdesc[0];
  if(g==0 && tid==0) desc[0] = sdesc[1];    // Cb
  // gather candidates from this WG's own slice (order-independent value set)
  int i = g*1024 + tid;
  double v = var[i];
  if(binof(v) == b0){
    unsigned idx = atomicAdd(cand_cnt, 1u);
    if(idx < CCAP) cand[idx] = (ull)__double_as_longlong(v);
  }
}

// ---------------- D3: radix select -> A -> chunk-0 ballot -> distributed embed ----------------
__global__ __launch_bounds__(1024) void k_sel(const float* __restrict__ cover,
    const int* __restrict__ secret, const double* __restrict__ var,
    const int* __restrict__ desc, const unsigned* __restrict__ cand_cnt,
    const ull* __restrict__ gcand, float* __restrict__ out){
  __shared__ ull scand[CCAP];               // 32 KB
  __shared__ unsigned hist[2048];           // 8 KB
  __shared__ unsigned wsum[16];
  __shared__ int spick[2];
  __shared__ int queue[ELIG];
  __shared__ unsigned wcnt[16];
  int tid = threadIdx.x, g = blockIdx.x;
  int lane = tid & 63, wid = tid >> 6;
  unsigned Ku = *cand_cnt;
  int K = (Ku < (unsigned)CCAP) ? (int)Ku : CCAP;
  for(int t=tid;t<K;t+=1024) scand[t]=gcand[t];
  int Cb = desc[0];
  __syncthreads();

  // ---- radix select rank (RANK0-Cb) among K candidates -> A bits ----
  int rk = RANK0 - Cb;
  const int sh[6] = {55,44,33,22,11,0};
  ull pref = 0ULL;
  for(int r=0;r<6;r++){
    for(int j=tid;j<2048;j+=1024) hist[j]=0u;
    __syncthreads();
    for(int t=tid;t<K;t+=1024){
      ull x = scand[t];
      bool match = (r==0) || ((x>>sh[r-1]) == (pref>>sh[r-1]));
      if(match) atomicAdd(&hist[(unsigned)((x>>sh[r]) & 2047ULL)], 1u);
    }
    __syncthreads();
    unsigned a0 = hist[2*tid], a1 = hist[2*tid+1], p2 = a0+a1;
    unsigned inc2 = p2;
#pragma unroll
    for(int off=1; off<64; off<<=1){
      unsigned t = __shfl_up(inc2, off);
      if(lane >= off) inc2 += t;
    }
    if(lane==63) wsum[wid]=inc2;
    __syncthreads();
    unsigned wpre=0;
#pragma unroll
    for(int w=0;w<16;w++) if(w<wid) wpre += wsum[w];
    inc2 += wpre;
    unsigned excl = inc2 - p2;
    if((unsigned)rk >= excl && (unsigned)rk < inc2){
      if((unsigned)rk < excl + a0){ spick[0]=2*tid;   spick[1]=(int)excl; }
      else                        { spick[0]=2*tid+1; spick[1]=(int)(excl+a0); }
    }
    __syncthreads();
    pref |= ((ull)spick[0]) << sh[r];
    rk   -= spick[1];
    __syncthreads();
  }
  double A = __longlong_as_double((long long)pref);  // sel <=> var > A

  // ---- chunk-0 ballot -> queue; distributed one-wave-per-block embed ----
  {
    int f = (var[tid] > A) ? 1 : 0;         // block id == tid (chunk 0)
    ull bal = __ballot(f);
    if(lane==0) wcnt[wid] = (unsigned)__popcll(bal);
    __syncthreads();
    int wpre=0, csum=0;
#pragma unroll
    for(int w=0;w<16;w++){
      int cc = (int)wcnt[w];
      if(w<wid) wpre += cc;
      csum += cc;
    }
    int P = wpre + (int)__popcll(bal & ((1ULL<<lane)-1ULL));
    if(f && P < ELIG) queue[P] = tid;
    __syncthreads();
    if(csum >= ELIG){
      // common path: first ELIG selected blocks all lie in chunk 0
      int W = g*16 + wid;                   // global wave id in [0,1536)
      if(W < ELIG) embed_one(cover, secret, out, queue[W], W, lane);
      return;
    }
  }

  // ---- rare fallback: WG0 alone runs the full chunked scan + 16-wave embed ----
  if(g != 0) return;
  __syncthreads();
  int total = 0;
  for(int chunk=0; chunk<96; chunk++){
    int ii = chunk*1024 + tid;
    int f = (var[ii] > A) ? 1 : 0;
    ull bal = __ballot(f);
    if(lane==0) wcnt[wid] = (unsigned)__popcll(bal);
    __syncthreads();
    int wpre=0, csum=0;
#pragma unroll
    for(int w=0;w<16;w++){
      int cc = (int)wcnt[w];
      if(w<wid) wpre += cc;
      csum += cc;
    }
    int P = total + wpre + (int)__popcll(bal & ((1ULL<<lane)-1ULL));
    if(f && P < ELIG) queue[P] = ii;
    total += csum;
    __syncthreads();
    if(total >= ELIG) break;
  }
  int nq = (total < ELIG) ? total : ELIG;
  for(int q = wid; q < nq; q += 16)
    embed_one(cover, secret, out, queue[q], q, lane);
}

// ---------------- host launch ----------------
extern "C" void kernel_launch(void* const* d_in, const int* in_sizes, int n_in,
                              void* d_out, int out_size, void* d_ws, size_t ws_size,
                              hipStream_t stream) {
  const float* cover  = (const float*)d_in[0];
  const int*   secret = (const int*)d_in[1];
  float* out = (float*)d_out;
  char*  ws  = (char*)d_ws;

  // ws layout (bytes)
  double*         var      = (double*)(ws);               // 98304*8    = 786432
  unsigned short* histp16  = (unsigned short*)(ws + 786432); // 512*96*2 -> 884736
  unsigned*       cand_cnt = (unsigned*)(ws + 884736);    // 4 (pad 16) -> 884752
  int*            desc     = (int*)(ws + 884752);         // 4 (pad 16) -> 884768
  ull*            cand     = (ull*)(ws + 884768);         // 4096*8     -> 917536

  k_stats<<<NWGS, 1024, 0, stream>>>(cover, out, var, histp16, cand_cnt);
  k_mid  <<<NWGS, 1024, 0, stream>>>(var, histp16, cand_cnt, cand, desc);
  k_sel  <<<NWGS, 1024, 0, stream>>>(cover, secret, var, desc, cand_cnt, cand, out);
}

// Round 13
// 58.757 us; speedup vs baseline: 3.3800x; 1.0475x over previous
//
#include <hip/hip_runtime.h>

// ---------------- problem constants ----------------
#define NBLK   98304     // 8*3*64*64 total 8x8 blocks
#define NPB    12288     // blocks per batch (3*64*64)
#define HW     512
#define NUMBITS 4096
#define RANK0  29490     // floor(0.3*(NBLK-1)); sel <=> var > s[RANK0] (adjacent order stats)
#define STEGO_N 6291456  // 8*3*512*512
#define ELIG   111       // ceil(4096/37) blocks contain eligible coefficients
#define HISTB  512       // fixed bins over variance range [0, 0.25]
#define CCAP   4096      // LDS candidate cap (bin-b0 population ~500)
#define SCAP   128       // per-slice candidate cap (expected ~5-6)
#define NWGS   96        // workgroups per kernel (1024 thr, 1 block/thread)

typedef unsigned long long ull;

// ---------------- DCT matrix as compile-time constants ----------------
struct DTab { double d[8][8]; };

constexpr double CT_[9] = {
  1.0,
  0.98078528040323044913,
  0.92387953251128675613,
  0.83146961230254523708,
  0.70710678118654752440,
  0.55557023301960222474,
  0.38268343236508977173,
  0.19509032201612826785,
  0.0
};
constexpr double cospi16(int m){           // cos(pi*m/16), m >= 0
  int r = m % 32;
  return (r<=8) ? CT_[r] : (r<=16) ? -CT_[16-r] : (r<=24) ? -CT_[r-16] : CT_[32-r];
}
constexpr DTab make_dtab(){
  DTab t{};
  for(int k=0;k<8;k++) for(int n=0;n<8;n++){
    double s = (k==0) ? 0.35355339059327376220 : 0.5; // sqrt(1/8), sqrt(2/8)
    t.d[k][n] = s * cospi16((2*n+1)*k);
  }
  return t;
}
constexpr DTab DT = make_dtab();

constexpr ull make_fmask(){ // bit u*8+v set iff 3 <= u+v <= 8
  ull m = 0;
  for(int u=0;u<8;u++) for(int v=0;v<8;v++){
    int s=u+v; if(s>=3 && s<=8) m |= (1ULL << (u*8+v));
  }
  return m;
}
constexpr ull FMASK = make_fmask();  // 37 bits set

__device__ __forceinline__ int binof(double v){
  int b = (int)(v * 2048.0);                // HISTB/0.25 — fixed, deterministic
  if(b > HISTB-1) b = HISTB-1;
  return b;                                 // v >= 0 always
}

// one WAVE embeds one block (global selected-rank S2); lane l owns coeff (l>>3,l&7)
__device__ __forceinline__ void embed_one(const float* __restrict__ cover,
    const int* __restrict__ secret, float* __restrict__ out, int bi, int S2, int lane){
  int lr = lane>>3, lc = lane&7;
  int m = bi & 63, n = (bi>>6)&63, bc = bi>>12, bb = bi / NPB;
  const float* p  = cover + ((size_t)bc*HW + (size_t)n*8)*HW + (size_t)m*8;
  float*       po = out   + ((size_t)bc*HW + (size_t)n*8)*HW + (size_t)m*8;
  double x = (double)p[(size_t)lr*HW + lc];     // X[lr][lc]
  // stage1: T1[r][v] = sum_j X[r][j]*D[v][j]
  double t1 = 0.0;
#pragma unroll
  for(int j=0;j<8;j++) t1 += __shfl(x, lr*8+j) * DT.d[lc][j];
  // stage2: C[u][v] = sum_k D[u][k]*T1[k][v]
  double coef = 0.0;
#pragma unroll
  for(int k=0;k<8;k++) coef += DT.d[lr][k] * __shfl(t1, k*8+lc);
  // embedding
  bool sel = (FMASK>>lane)&1ULL;
  float mv = 0.f;
  if(sel){
    int fp  = (int)__popcll(FMASK & ((1ULL<<lane)-1ULL));
    int ord = 37*S2 + fp;
    if(ord < NUMBITS){
      mv = 1.f;
      double rnd = rint(coef);                  // round half-to-even == jnp.round
      int lsb = ((int)fabs(rnd)) & 1;
      int bit = secret[(size_t)bb*NUMBITS + ord];
      if(lsb != bit) coef += ((coef>=0.0)?1.0:-1.0)*(2.0*(double)bit-1.0)*0.5;
    }
  }
  out[(size_t)STEGO_N + (size_t)bi*64 + lane] = mv;
  // inv stage1: T2[r][v] = sum_u D[u][r]*M[u][v]
  double t2 = 0.0;
#pragma unroll
  for(int u=0;u<8;u++) t2 += DT.d[u][lr] * __shfl(coef, u*8+lc);
  // inv stage2: pix[r][k] = sum_q T2[r][q]*D[q][k]
  double px = 0.0;
#pragma unroll
  for(int qq=0;qq<8;qq++) px += __shfl(t2, lr*8+qq) * DT.d[qq][lc];
  po[(size_t)lr*HW + lc] = (float)px;
}

// ---------------- D1: copy + map-zero + variance + transposed ushort hist ----------------
__global__ __launch_bounds__(1024) void k_stats(const float* __restrict__ cover,
    float* __restrict__ out, double* __restrict__ var,
    unsigned short* __restrict__ histp16, unsigned* __restrict__ flags){
  __shared__ unsigned h[HISTB];             // 2 KB
  int tid = threadIdx.x, g = blockIdx.x;
  int i = g*1024 + tid;                     // block id over (b,c,n,m)
  if(tid < HISTB) h[tid]=0u;
  if(tid==0) flags[g] = 0u;                 // handshake flag for D2 (plain store)
  int m = i & 63, n = (i>>6)&63, bc = i>>12;
  const float* p  = cover + ((size_t)bc*HW + (size_t)n*8)*HW + (size_t)m*8;
  float*       po = out   + ((size_t)bc*HW + (size_t)n*8)*HW + (size_t)m*8;
  double s1=0.0, s2=0.0;
#pragma unroll
  for(int r=0;r<8;r++){
    const float4* q = (const float4*)(p + (size_t)r*HW);
    float4 a = q[0], b = q[1];
    float4* w = (float4*)(po + (size_t)r*HW);
    w[0]=a; w[1]=b;
    double x;
    x=(double)a.x; s1+=x; s2+=x*x;
    x=(double)a.y; s1+=x; s2+=x*x;
    x=(double)a.z; s1+=x; s2+=x*x;
    x=(double)a.w; s1+=x; s2+=x*x;
    x=(double)b.x; s1+=x; s2+=x*x;
    x=(double)b.y; s1+=x; s2+=x*x;
    x=(double)b.z; s1+=x; s2+=x*x;
    x=(double)b.w; s1+=x; s2+=x*x;
  }
  double mean = s1*(1.0/64.0);
  double v = s2*(1.0/64.0) - mean*mean;
  if(v < 0.0) v = 0.0;
  var[i] = v;
  // zero this block's embedding map (fixed up later for eligible blocks)
  float4 z = make_float4(0.f,0.f,0.f,0.f);
  float4* pm = (float4*)(out + (size_t)STEGO_N + (size_t)i*64);
#pragma unroll
  for(int j=0;j<16;j++) pm[j] = z;
  // per-WG LDS histogram -> transposed ushort slot (row = bin, col = WG)
  __syncthreads();
  atomicAdd(&h[binof(v)], 1u);
  __syncthreads();
  if(tid < HISTB) histp16[(size_t)tid*NWGS + g] = (unsigned short)h[tid];
}

// ---------------- D2: hist reduce -> gather -> handshake -> select -> embed ----------------
__global__ __launch_bounds__(1024) void k_rest(const float* __restrict__ cover,
    const int* __restrict__ secret, const double* __restrict__ var,
    const unsigned short* __restrict__ histp16, unsigned* __restrict__ flags,
    ull* __restrict__ gcand, float* __restrict__ out){
  __shared__ ull scand[CCAP];               // 32 KB
  __shared__ unsigned hist[2048];           // 8 KB
  __shared__ unsigned wsum[16];
  __shared__ int sdesc[2];                  // b0, Cb
  __shared__ int spick[2];
  __shared__ int scnt[NWGS];
  __shared__ int soff[NWGS+1];
  __shared__ unsigned s_lc, s_k;
  __shared__ int s_bad;
  __shared__ int queue[ELIG];
  __shared__ unsigned wcnt[16];
  int tid = threadIdx.x, g = blockIdx.x;
  int lane = tid & 63, wid = tid >> 6;

  // ---- A: reduce hist rows (vectorized) -> b0, Cb (redundant per WG) ----
  unsigned part = 0, incl = 0;
  if(tid < HISTB){
    const uint4* row = (const uint4*)(histp16 + (size_t)tid*NWGS);
#pragma unroll
    for(int j=0;j<12;j++){
      uint4 w = row[j];
      part += (w.x&0xFFFFu)+(w.x>>16)+(w.y&0xFFFFu)+(w.y>>16)
            + (w.z&0xFFFFu)+(w.z>>16)+(w.w&0xFFFFu)+(w.w>>16);
    }
    incl = part;
#pragma unroll
    for(int off=1; off<64; off<<=1){
      unsigned t = __shfl_up(incl, off);
      if(lane >= off) incl += t;
    }
    if(lane==63) wsum[wid]=incl;
  }
  if(tid==0){ s_lc=0u; s_k=0u; s_bad=0; }
  __syncthreads();
  if(tid < HISTB){
    unsigned wpre=0;
#pragma unroll
    for(int w=0;w<8;w++) if(w<wid) wpre += wsum[w];
    unsigned c = wpre + incl - part;        // exclusive prefix of bin 'tid'
    if((unsigned)RANK0 >= c && (unsigned)RANK0 < c+part){ sdesc[0]=tid; sdesc[1]=(int)c; }
  }
  __syncthreads();
  int b0 = sdesc[0], Cb = sdesc[1];

  // ---- B: gather own slice's bin-b0 values -> private global slot, release flag ----
  {
    double v = var[g*1024 + tid];
    if(binof(v) == b0){
      unsigned idx = atomicAdd(&s_lc, 1u);
      if(idx < SCAP) gcand[(size_t)g*SCAP + idx] = (ull)__double_as_longlong(v);
    }
    __syncthreads();
    if(tid==0){
      __threadfence();                      // make gcand writes agent-visible
      __hip_atomic_store(&flags[g], s_lc+1u, __ATOMIC_RELEASE, __HIP_MEMORY_SCOPE_AGENT);
    }
  }

  // ---- C: wait for all 96 slices' candidates; bounded spin with sweep fallback ----
  if(tid < NWGS){
    unsigned f = 0; int it = 0;
    for(;;){
      f = __hip_atomic_load(&flags[tid], __ATOMIC_ACQUIRE, __HIP_MEMORY_SCOPE_AGENT);
      if(f) break;
      if(++it > (1<<18)) break;
      __builtin_amdgcn_s_sleep(8);
    }
    scnt[tid] = (int)f - 1;                 // -1 on timeout
  }
  __syncthreads();
  if(tid < NWGS && scnt[tid] < 0) atomicOr(&s_bad, 1);
  __syncthreads();
  int K;
  if(!s_bad){
    if(tid==0){
      int c=0;
      for(int w=0;w<NWGS;w++){
        int cc = scnt[w]; if(cc > SCAP) cc = SCAP;
        soff[w]=c; c+=cc;
      }
      soff[NWGS]=c;
    }
    __syncthreads();
    K = soff[NWGS]; if(K > CCAP) K = CCAP;
    if(tid < NWGS){
      int cc = scnt[tid]; if(cc > SCAP) cc = SCAP;
      int o = soff[tid];
      for(int j=0;j<cc;j++){
        int d = o+j;
        if(d < CCAP) scand[d] = gcand[(size_t)tid*SCAP + j];
      }
    }
    __syncthreads();
  }else{
    // fallback: sweep the whole var array ourselves (same multiset -> same A)
    const double4* v4 = (const double4*)var;
    for(int j=tid; j<24576; j+=1024){
      double4 v = v4[j];
      double vv[4] = {v.x, v.y, v.z, v.w};
#pragma unroll
      for(int e=0;e<4;e++){
        if(binof(vv[e]) == b0){
          unsigned idx = atomicAdd(&s_k, 1u);
          if(idx < CCAP) scand[idx] = (ull)__double_as_longlong(vv[e]);
        }
      }
    }
    __syncthreads();
    K = (s_k < (unsigned)CCAP) ? (int)s_k : CCAP;
  }

  // ---- D: radix select rank (RANK0-Cb) among K candidates -> A bits ----
  int rk = RANK0 - Cb;
  const int sh[6] = {55,44,33,22,11,0};
  ull pref = 0ULL;
  for(int r=0;r<6;r++){
    for(int j=tid;j<2048;j+=1024) hist[j]=0u;
    __syncthreads();
    for(int t=tid;t<K;t+=1024){
      ull x = scand[t];
      bool match = (r==0) || ((x>>sh[r-1]) == (pref>>sh[r-1]));
      if(match) atomicAdd(&hist[(unsigned)((x>>sh[r]) & 2047ULL)], 1u);
    }
    __syncthreads();
    unsigned a0 = hist[2*tid], a1 = hist[2*tid+1], p2 = a0+a1;
    unsigned inc2 = p2;
#pragma unroll
    for(int off=1; off<64; off<<=1){
      unsigned t = __shfl_up(inc2, off);
      if(lane >= off) inc2 += t;
    }
    if(lane==63) wsum[wid]=inc2;
    __syncthreads();
    unsigned wpre=0;
#pragma unroll
    for(int w=0;w<16;w++) if(w<wid) wpre += wsum[w];
    inc2 += wpre;
    unsigned excl = inc2 - p2;
    if((unsigned)rk >= excl && (unsigned)rk < inc2){
      if((unsigned)rk < excl + a0){ spick[0]=2*tid;   spick[1]=(int)excl; }
      else                        { spick[0]=2*tid+1; spick[1]=(int)(excl+a0); }
    }
    __syncthreads();
    pref |= ((ull)spick[0]) << sh[r];
    rk   -= spick[1];
    __syncthreads();
  }
  double A = __longlong_as_double((long long)pref);  // sel <=> var > A

  // ---- E: chunk-0 ballot -> queue; distributed one-wave-per-block embed ----
  {
    int f = (var[tid] > A) ? 1 : 0;         // block id == tid (chunk 0)
    ull bal = __ballot(f);
    if(lane==0) wcnt[wid] = (unsigned)__popcll(bal);
    __syncthreads();
    int wpre=0, csum=0;
#pragma unroll
    for(int w=0;w<16;w++){
      int cc = (int)wcnt[w];
      if(w<wid) wpre += cc;
      csum += cc;
    }
    int P = wpre + (int)__popcll(bal & ((1ULL<<lane)-1ULL));
    if(f && P < ELIG) queue[P] = tid;
    __syncthreads();
    if(csum >= ELIG){
      // common path: first ELIG selected blocks all lie in chunk 0
      int W = g*16 + wid;                   // global wave id in [0,1536)
      if(W < ELIG) embed_one(cover, secret, out, queue[W], W, lane);
      return;
    }
  }

  // ---- rare fallback: WG0 alone runs the full chunked scan + 16-wave embed ----
  if(g != 0) return;
  __syncthreads();
  int total = 0;
  for(int chunk=0; chunk<96; chunk++){
    int ii = chunk*1024 + tid;
    int f = (var[ii] > A) ? 1 : 0;
    ull bal = __ballot(f);
    if(lane==0) wcnt[wid] = (unsigned)__popcll(bal);
    __syncthreads();
    int wpre=0, csum=0;
#pragma unroll
    for(int w=0;w<16;w++){
      int cc = (int)wcnt[w];
      if(w<wid) wpre += cc;
      csum += cc;
    }
    int P = total + wpre + (int)__popcll(bal & ((1ULL<<lane)-1ULL));
    if(f && P < ELIG) queue[P] = ii;
    total += csum;
    __syncthreads();
    if(total >= ELIG) break;
  }
  int nq = (total < ELIG) ? total : ELIG;
  for(int q = wid; q < nq; q += 16)
    embed_one(cover, secret, out, queue[q], q, lane);
}

// ---------------- host launch ----------------
extern "C" void kernel_launch(void* const* d_in, const int* in_sizes, int n_in,
                              void* d_out, int out_size, void* d_ws, size_t ws_size,
                              hipStream_t stream) {
  const float* cover  = (const float*)d_in[0];
  const int*   secret = (const int*)d_in[1];
  float* out = (float*)d_out;
  char*  ws  = (char*)d_ws;

  // ws layout (bytes)
  double*         var     = (double*)(ws);                  // 98304*8   = 786432
  unsigned short* histp16 = (unsigned short*)(ws + 786432); // 512*96*2  -> 884736
  unsigned*       flags   = (unsigned*)(ws + 884736);       // 96*4      -> 885120
  ull*            gcand   = (ull*)(ws + 885120);            // 96*128*8  -> 983424

  k_stats<<<NWGS, 1024, 0, stream>>>(cover, out, var, histp16, flags);
  k_rest <<<NWGS, 1024, 0, stream>>>(cover, secret, var, histp16, flags, gcand, out);
}